// Round 8
// baseline (626.755 us; speedup 1.0000x reference)
//
#include <hip/hip_runtime.h>
#include <math.h>

#define C 256
#define DH 32
#define NH 8
#define NL 4
#define NP 4
#define BQ 4
#define LQ 900
#define LVTOT 17821
#define DFFN 2048
#define NTOK (BQ*LQ)          // 3600 token rows, token index t = lq*B + b

typedef __attribute__((ext_vector_type(8))) short bf8_t;    // 8 bf16 (4 VGPRs)
typedef __attribute__((ext_vector_type(4))) float f4_t;     // MFMA acc
typedef __attribute__((ext_vector_type(8))) unsigned short us8_t;
typedef __attribute__((ext_vector_type(4))) unsigned short us4_t;

// ---------------- helpers ----------------
__device__ __forceinline__ float block_sum256(float v, float* pr) {
    int t = threadIdx.x, lane = t & 63, wv = t >> 6;
#pragma unroll
    for (int o = 32; o > 0; o >>= 1) v += __shfl_down(v, o, 64);
    if (lane == 0) pr[wv] = v;
    __syncthreads();
    float r = pr[0] + pr[1] + pr[2] + pr[3];
    __syncthreads();
    return r;
}

__device__ __forceinline__ unsigned short f2bf(float f) {
    unsigned int u = __float_as_uint(f);
    u += 0x7fffu + ((u >> 16) & 1u);   // round-to-nearest-even
    return (unsigned short)(u >> 16);
}
__device__ __forceinline__ float b2f(unsigned short u) {
    return __uint_as_float(((unsigned int)u) << 16);
}

// ---------------- bf16 MFMA GEMM: Y = act(A @ W^T + b) ----------------
// A: [nrows][KS] fp32 (AB=0) or bf16 (AB=1); W: [OC][KS] fp32.
// Output f32 (OB=0) or bf16 (OB=1). Tile 128x128, 4 waves 2x2 (wave=64x64), K-step 32.
enum { MODE_NORMAL = 0, MODE_RELU = 1, MODE_VALUE = 2, MODE_QKV = 3 };

#define LDP 72   // LDS row stride in bf16 elems (144 B = 9*16B: aligned b128)

template<int K, int KS, int MODE, int AB, int OB>
__global__ void k_mgemm(const void* __restrict__ A_, const float* __restrict__ W,
                        const float* __restrict__ bias, void* __restrict__ Y_, int nrows) {
    __shared__ unsigned short Ash[128 * LDP];
    __shared__ unsigned short Bsh[128 * LDP];
    int t = threadIdx.x;
    int lane = t & 63, w = t >> 6;
    int wm = w & 1, wn = w >> 1;
    int r0 = blockIdx.x * 128;
    int c0 = blockIdx.y * 128;

    f4_t acc[4][4];
#pragma unroll
    for (int mt = 0; mt < 4; ++mt)
#pragma unroll
        for (int nt = 0; nt < 4; ++nt) acc[mt][nt] = (f4_t)0.f;

    int arow = t >> 1;                 // 0..127
    int akoff = (t & 1) * 16;          // 0 or 16
    int asrc = min(r0 + arow, nrows - 1);
    const float* aptrf = (const float*)A_ + (size_t)asrc * KS + akoff;
    const unsigned short* aptrh = (const unsigned short*)A_ + (size_t)asrc * KS + akoff;
    unsigned short* adst = &Ash[arow * LDP + akoff];

    const float* bptr = W + (size_t)(c0 + arow) * KS + akoff;
    unsigned short* bdst = &Bsh[arow * LDP + akoff];

    int lr = lane & 15, kg = lane >> 4;

    for (int k0 = 0; k0 < K; k0 += 32) {
        __syncthreads();
        if (AB) {
            *(us8_t*)(adst) = *(const us8_t*)(aptrh + k0);
            *(us8_t*)(adst + 8) = *(const us8_t*)(aptrh + k0 + 8);
        } else {
            float4 av0 = *(const float4*)(aptrf + k0);
            float4 av1 = *(const float4*)(aptrf + k0 + 4);
            float4 av2 = *(const float4*)(aptrf + k0 + 8);
            float4 av3 = *(const float4*)(aptrf + k0 + 12);
            us8_t u0, u1;
            u0[0]=f2bf(av0.x); u0[1]=f2bf(av0.y); u0[2]=f2bf(av0.z); u0[3]=f2bf(av0.w);
            u0[4]=f2bf(av1.x); u0[5]=f2bf(av1.y); u0[6]=f2bf(av1.z); u0[7]=f2bf(av1.w);
            u1[0]=f2bf(av2.x); u1[1]=f2bf(av2.y); u1[2]=f2bf(av2.z); u1[3]=f2bf(av2.w);
            u1[4]=f2bf(av3.x); u1[5]=f2bf(av3.y); u1[6]=f2bf(av3.z); u1[7]=f2bf(av3.w);
            *(us8_t*)(adst) = u0;
            *(us8_t*)(adst + 8) = u1;
        }
        {
            float4 bv0 = *(const float4*)(bptr + k0);
            float4 bv1 = *(const float4*)(bptr + k0 + 4);
            float4 bv2 = *(const float4*)(bptr + k0 + 8);
            float4 bv3 = *(const float4*)(bptr + k0 + 12);
            us8_t u0, u1;
            u0[0]=f2bf(bv0.x); u0[1]=f2bf(bv0.y); u0[2]=f2bf(bv0.z); u0[3]=f2bf(bv0.w);
            u0[4]=f2bf(bv1.x); u0[5]=f2bf(bv1.y); u0[6]=f2bf(bv1.z); u0[7]=f2bf(bv1.w);
            u1[0]=f2bf(bv2.x); u1[1]=f2bf(bv2.y); u1[2]=f2bf(bv2.z); u1[3]=f2bf(bv2.w);
            u1[4]=f2bf(bv3.x); u1[5]=f2bf(bv3.y); u1[6]=f2bf(bv3.z); u1[7]=f2bf(bv3.w);
            *(us8_t*)(bdst) = u0;
            *(us8_t*)(bdst + 8) = u1;
        }
        __syncthreads();

        bf8_t afr[4], bfr[4];
#pragma unroll
        for (int mt = 0; mt < 4; ++mt)
            afr[mt] = *(const bf8_t*)&Ash[(wm * 64 + mt * 16 + lr) * LDP + kg * 8];
#pragma unroll
        for (int nt = 0; nt < 4; ++nt)
            bfr[nt] = *(const bf8_t*)&Bsh[(wn * 64 + nt * 16 + lr) * LDP + kg * 8];
#pragma unroll
        for (int mt = 0; mt < 4; ++mt)
#pragma unroll
            for (int nt = 0; nt < 4; ++nt)
                acc[mt][nt] = __builtin_amdgcn_mfma_f32_16x16x32_bf16(afr[mt], bfr[nt], acc[mt][nt], 0, 0, 0);
    }

#pragma unroll
    for (int mt = 0; mt < 4; ++mt) {
#pragma unroll
        for (int nt = 0; nt < 4; ++nt) {
            int col = c0 + wn * 64 + nt * 16 + lr;
            float b0 = bias ? bias[col] : 0.f;
#pragma unroll
            for (int rr = 0; rr < 4; ++rr) {
                int row = r0 + wm * 64 + mt * 16 + kg * 4 + rr;
                if (row >= nrows) continue;
                float v = acc[mt][nt][rr] + b0;
                size_t idx;
                if (MODE == MODE_NORMAL) {
                    idx = (size_t)row * (gridDim.y * 128) + col;
                } else if (MODE == MODE_RELU) {
                    v = fmaxf(v, 0.f);
                    idx = (size_t)row * (gridDim.y * 128) + col;
                } else if (MODE == MODE_VALUE) {
                    int lv = row >> 2, b = row & 3;
                    int h = col >> 5, d = col & 31;
                    idx = (((size_t)b * NH + h) * LVTOT + lv) * DH + d;
                } else { // MODE_QKV
                    int lq = row >> 2, b = row & 3;
                    int part = col >> 8, cc = col & 255;
                    int h = cc >> 5, d = cc & 31;
                    if (part == 0) v *= 0.17677669529663687f;  // 1/sqrt(32)
                    idx = (size_t)part * (BQ * NH * LQ * DH) + (((size_t)b * NH + h) * LQ + lq) * DH + d;
                }
                if (OB) ((unsigned short*)Y_)[idx] = f2bf(v);
                else    ((float*)Y_)[idx] = v;
            }
        }
    }
}

// ---------------- deformable sampling: block = (bh, 20-query tile) ----------------
// grid = 45*32; bh = blk&31 so blk%8 == bh%8 -> all blocks of a bh on one XCD,
// each XCD serves 4 value slabs (4 x 1.14 MB) ~ L2-resident.
#define SQT 20

__global__ void k_sample(const float* __restrict__ trp, const float* __restrict__ off,
                         const float* __restrict__ awl, const unsigned short* __restrict__ value,
                         unsigned short* __restrict__ accU) {
    int blk = blockIdx.x;
    int bh = blk & 31;
    int qt = blk >> 5;               // 0..44
    int b = bh >> 3, h = bh & 7;
    int t = threadIdx.x;
    int qi = t >> 5, d = t & 31;
    const int Hs[4] = {100, 50, 25, 13};
    const int Ws[4] = {134, 67, 34, 17};
    const int Ss[4] = {0, 13400, 16750, 17600};
    const unsigned short* vb = value + (size_t)bh * LVTOT * DH;

    for (int q = qt * SQT + qi; q < qt * SQT + SQT; q += 8) {
        int r = q * BQ + b;
        // per-head softmax over 16 logits (redundant across the 32 d-lanes)
        const float* lg = awl + (size_t)r * 128 + h * 16;
        float lv[16];
#pragma unroll
        for (int i = 0; i < 4; ++i) {
            float4 qv = *(const float4*)(lg + i * 4);
            lv[i*4+0] = qv.x; lv[i*4+1] = qv.y; lv[i*4+2] = qv.z; lv[i*4+3] = qv.w;
        }
        float mx = -1e30f;
#pragma unroll
        for (int i = 0; i < 16; ++i) mx = fmaxf(mx, lv[i]);
        float ssum = 0.f;
#pragma unroll
        for (int i = 0; i < 16; ++i) { lv[i] = __expf(lv[i] - mx); ssum += lv[i]; }
        float sinv = 1.0f / ssum;

        const float* offr = off + (size_t)r * C + h * 32;
        float a = 0.f;
#pragma unroll
        for (int l = 0; l < 4; ++l) {
            float rx = trp[((size_t)r * NL + l) * 2 + 0];
            float ry = trp[((size_t)r * NL + l) * 2 + 1];
            int Hl = Hs[l], Wl = Ws[l], s = Ss[l];
            float fW = (float)Wl, fH = (float)Hl;
#pragma unroll
            for (int p = 0; p < 4; ++p) {
                float ox = offr[(l * NP + p) * 2 + 0];
                float oy = offr[(l * NP + p) * 2 + 1];
                float wq = lv[l * 4 + p] * sinv;
                float x = (rx + ox / fW) * fW - 0.5f;
                float y = (ry + oy / fH) * fH - 0.5f;
                float x0 = floorf(x), y0 = floorf(y);
                float sum = 0.f;
#pragma unroll
                for (int dy = 0; dy < 2; ++dy) {
#pragma unroll
                    for (int dx = 0; dx < 2; ++dx) {
                        float xi = x0 + dx, yi = y0 + dy;
                        float wgt = (1.0f - fabsf(x - xi)) * (1.0f - fabsf(y - yi));
                        bool valid = (xi >= 0.f) && (xi < fW) && (yi >= 0.f) && (yi < fH);
                        int xic = min(max((int)xi, 0), Wl - 1);
                        int yic = min(max((int)yi, 0), Hl - 1);
                        float v = b2f(vb[((size_t)s + yic * Wl + xic) * DH + d]);
                        sum += (valid ? wgt : 0.f) * v;
                    }
                }
                a += wq * sum;
            }
        }
        accU[(size_t)r * C + h * 32 + d] = f2bf(a);
    }
}

// ---------------- residual + LN ----------------
__global__ void k_res_ln(const float* __restrict__ Yin, const float* __restrict__ Xres,
                         const float* __restrict__ g, const float* __restrict__ be,
                         float* __restrict__ out) {
    __shared__ float pr[4];
    int r = blockIdx.x, t = threadIdx.x;
    float v = Yin[(size_t)r * C + t] + Xres[(size_t)r * C + t];
    float mean = block_sum256(v, pr) * (1.0f / C);
    float dv = v - mean;
    float var = block_sum256(dv * dv, pr) * (1.0f / C);
    out[(size_t)r * C + t] = dv * rsqrtf(var + 1e-5f) * g[t] + be[t];
}

__global__ void k_res_ln2(const float* __restrict__ Y0, const float* __restrict__ Y1,
                          const float* __restrict__ Xres,
                          const float* __restrict__ g, const float* __restrict__ be,
                          float* __restrict__ out) {
    __shared__ float pr[4];
    int r = blockIdx.x, t = threadIdx.x;
    float v = Y0[(size_t)r * C + t] + Y1[(size_t)r * C + t] + Xres[(size_t)r * C + t];
    float mean = block_sum256(v, pr) * (1.0f / C);
    float dv = v - mean;
    float var = block_sum256(dv * dv, pr) * (1.0f / C);
    out[(size_t)r * C + t] = dv * rsqrtf(var + 1e-5f) * g[t] + be[t];
}

// ---------------- MFMA flash attention (bf16 Q/K/V/O) ----------------
#define NQC3 15   // ceil(900/64)

__global__ __launch_bounds__(256, 1)
void k_attn3(const unsigned short* __restrict__ Q, const unsigned short* __restrict__ K,
             const unsigned short* __restrict__ V, unsigned short* __restrict__ O) {
    __shared__ unsigned short sK[4][64 * 72];   // K rows [key][d]
    __shared__ unsigned short sV[4][32 * 72];   // V^T [d][key]
    __shared__ float sPO[4][64 * 36];           // P bf16 [64q][72k] overlaid, then Obuf f32 [64q][36d]
    __shared__ float sWm[4][64], sWl[4][64];

    int blk = blockIdx.x;
    int bh = blk & 31;                 // XCD locality
    int qc = blk >> 5;
    int b = bh >> 3, h = bh & 7;
    int t = threadIdx.x;
    int w = t >> 6, lane = t & 63;
    int lr = lane & 15, g = lane >> 4;

    const unsigned short* Qb = Q + (size_t)bh * LQ * DH;
    const unsigned short* Kb = K + (size_t)bh * LQ * DH;
    const unsigned short* Vb = V + (size_t)bh * LQ * DH;

    unsigned short* Ks = sK[w];
    unsigned short* Vt = sV[w];
    unsigned short* Ps = (unsigned short*)sPO[w];

    bf8_t qf[4];
#pragma unroll
    for (int nt = 0; nt < 4; ++nt) {
        int qg = min(qc * 64 + nt * 16 + lr, LQ - 1);
        qf[nt] = *(const bf8_t*)(Qb + (size_t)qg * DH + g * 8);
    }

    float m[4], l[4];
    f4_t acc[2][4];
#pragma unroll
    for (int nt = 0; nt < 4; ++nt) {
        m[nt] = -3e38f; l[nt] = 0.f;
        acc[0][nt] = (f4_t)0.f; acc[1][nt] = (f4_t)0.f;
    }

    for (int ci = 0; ci < 4; ++ci) {
        int k0 = ci * 256 + w * 64;
        if (k0 >= LQ) break;
        int kgl = min(k0 + lane, LQ - 1);
        const unsigned short* kr = Kb + (size_t)kgl * DH;
        const unsigned short* vr = Vb + (size_t)kgl * DH;
#pragma unroll
        for (int i = 0; i < 4; ++i)
            *(us8_t*)&Ks[lane * 72 + i * 8] = *(const us8_t*)(kr + i * 8);
#pragma unroll
        for (int i = 0; i < 4; ++i) {
            us8_t v8 = *(const us8_t*)(vr + i * 8);
#pragma unroll
            for (int j = 0; j < 8; ++j)
                Vt[(i * 8 + j) * 72 + lane] = v8[j];
        }
        // ---- QK^T: S^T[64k][64q] ----
        bf8_t ka[4];
#pragma unroll
        for (int mt = 0; mt < 4; ++mt)
            ka[mt] = *(const bf8_t*)&Ks[(mt * 16 + lr) * 72 + g * 8];
        f4_t st[4][4];
#pragma unroll
        for (int mt = 0; mt < 4; ++mt)
#pragma unroll
            for (int nt = 0; nt < 4; ++nt)
                st[mt][nt] = __builtin_amdgcn_mfma_f32_16x16x32_bf16(ka[mt], qf[nt], (f4_t)0.f, 0, 0, 0);
        // ---- online softmax + P write ----
#pragma unroll
        for (int nt = 0; nt < 4; ++nt) {
            float sv[4][4];
            float cm = -3e38f;
#pragma unroll
            for (int mt = 0; mt < 4; ++mt)
#pragma unroll
                for (int rr = 0; rr < 4; ++rr) {
                    bool valid = (k0 + mt * 16 + g * 4 + rr) < LQ;
                    float s = valid ? st[mt][nt][rr] : -3e38f;
                    sv[mt][rr] = s;
                    cm = fmaxf(cm, s);
                }
            cm = fmaxf(cm, __shfl_xor(cm, 16, 64));
            cm = fmaxf(cm, __shfl_xor(cm, 32, 64));
            float mn = fmaxf(m[nt], cm);
            float sc = __expf(m[nt] - mn);
            float cs = 0.f;
#pragma unroll
            for (int mt = 0; mt < 4; ++mt) {
                us4_t pk;
#pragma unroll
                for (int rr = 0; rr < 4; ++rr) {
                    float p = (sv[mt][rr] > -1e37f) ? __expf(sv[mt][rr] - mn) : 0.f;
                    cs += p;
                    pk[rr] = f2bf(p);
                }
                *(us4_t*)&Ps[(nt * 16 + lr) * 72 + mt * 16 + g * 4] = pk;
            }
            cs += __shfl_xor(cs, 16, 64);
            cs += __shfl_xor(cs, 32, 64);
            l[nt] = l[nt] * sc + cs;
            m[nt] = mn;
            acc[0][nt] *= sc;
            acc[1][nt] *= sc;
        }
        // ---- PV: O^T[32d][64q] ----
        bf8_t va[2][2];
#pragma unroll
        for (int md = 0; md < 2; ++md)
#pragma unroll
            for (int kt = 0; kt < 2; ++kt)
                va[md][kt] = *(const bf8_t*)&Vt[(md * 16 + lr) * 72 + kt * 32 + g * 8];
#pragma unroll
        for (int nt = 0; nt < 4; ++nt)
#pragma unroll
            for (int kt = 0; kt < 2; ++kt) {
                bf8_t pb = *(const bf8_t*)&Ps[(nt * 16 + lr) * 72 + kt * 32 + g * 8];
                acc[0][nt] = __builtin_amdgcn_mfma_f32_16x16x32_bf16(va[0][kt], pb, acc[0][nt], 0, 0, 0);
                acc[1][nt] = __builtin_amdgcn_mfma_f32_16x16x32_bf16(va[1][kt], pb, acc[1][nt], 0, 0, 0);
            }
    }

    // ---- wave combine ----
    if (g == 0) {
#pragma unroll
        for (int nt = 0; nt < 4; ++nt) {
            sWm[w][nt * 16 + lr] = m[nt];
            sWl[w][nt * 16 + lr] = l[nt];
        }
    }
    __syncthreads();
    float* ob = sPO[w];
#pragma unroll
    for (int nt = 0; nt < 4; ++nt) {
        int q = nt * 16 + lr;
        float M = fmaxf(fmaxf(sWm[0][q], sWm[1][q]), fmaxf(sWm[2][q], sWm[3][q]));
        float fac = __expf(m[nt] - M);
        f4_t v0 = acc[0][nt] * fac;
        f4_t v1 = acc[1][nt] * fac;
        *(f4_t*)&ob[q * 36 + g * 4] = v0;
        *(f4_t*)&ob[q * 36 + 16 + g * 4] = v1;
    }
    __syncthreads();
    {
        int q = t >> 2, d0 = (t & 3) * 8;
        int qglob = qc * 64 + q;
        if (qglob < LQ) {
            float M = fmaxf(fmaxf(sWm[0][q], sWm[1][q]), fmaxf(sWm[2][q], sWm[3][q]));
            float L = 0.f;
#pragma unroll
            for (int w2 = 0; w2 < 4; ++w2) L += sWl[w2][q] * __expf(sWm[w2][q] - M);
            float inv = 1.0f / L;
            f4_t r0 = (f4_t)0.f, r1 = (f4_t)0.f;
#pragma unroll
            for (int w2 = 0; w2 < 4; ++w2) {
                r0 += *(f4_t*)&sPO[w2][q * 36 + d0];
                r1 += *(f4_t*)&sPO[w2][q * 36 + d0 + 4];
            }
            r0 *= inv; r1 *= inv;
            us8_t u;
#pragma unroll
            for (int j = 0; j < 4; ++j) { u[j] = f2bf(r0[j]); u[4 + j] = f2bf(r1[j]); }
            *(us8_t*)(O + ((size_t)(qglob * BQ + b)) * C + h * 32 + d0) = u;
        }
    }
}

// ---------------- launch ----------------
extern "C" void kernel_launch(void* const* d_in, const int* in_sizes, int n_in,
                              void* d_out, int out_size, void* d_ws, size_t ws_size,
                              hipStream_t stream) {
    const float* tgt      = (const float*)d_in[0];
    const float* trp      = (const float*)d_in[1];
    const float* memory   = (const float*)d_in[2];
    const float* vproj_w  = (const float*)d_in[5];  const float* vproj_b  = (const float*)d_in[6];
    const float* off_w    = (const float*)d_in[7];  const float* off_b    = (const float*)d_in[8];
    const float* aw_w     = (const float*)d_in[9];  const float* aw_b     = (const float*)d_in[10];
    const float* oproj_w  = (const float*)d_in[11]; const float* oproj_b  = (const float*)d_in[12];
    const float* ln1_g    = (const float*)d_in[13]; const float* ln1_b    = (const float*)d_in[14];
    const float* sa_in_w  = (const float*)d_in[15]; const float* sa_in_b  = (const float*)d_in[16];
    const float* sa_out_w = (const float*)d_in[17]; const float* sa_out_b = (const float*)d_in[18];
    const float* ln2_g    = (const float*)d_in[19]; const float* ln2_b    = (const float*)d_in[20];
    const float* l1_w     = (const float*)d_in[21]; const float* l1_b     = (const float*)d_in[22];
    const float* l2_w     = (const float*)d_in[23]; const float* l2_b     = (const float*)d_in[24];
    const float* ln3_g    = (const float*)d_in[25]; const float* ln3_b    = (const float*)d_in[26];
    const float* sa3_in_w = (const float*)d_in[27]; const float* sa3_in_b = (const float*)d_in[28];
    const float* sa3_out_w= (const float*)d_in[29]; const float* sa3_out_b= (const float*)d_in[30];
    const float* ln5_g    = (const float*)d_in[31]; const float* ln5_b    = (const float*)d_in[32];
    const float* l31_w    = (const float*)d_in[33]; const float* l31_b    = (const float*)d_in[34];
    const float* l32_w    = (const float*)d_in[35]; const float* l32_b    = (const float*)d_in[36];
    const float* ln33_g   = (const float*)d_in[37]; const float* ln33_b   = (const float*)d_in[38];

    float* ws = (float*)d_ws;
    float* X              = ws;                                    // 921,600 f32
    unsigned short* valueU= (unsigned short*)(ws + 921600);        // 18,248,704 bf16
    float* off            = ws + 10045952;                         // 921,600 f32
    float* aw             = ws + 10967552;                         // 460,800 f32
    unsigned short* accU  = (unsigned short*)(ws + 11428352);      // 921,600 bf16
    unsigned short* QKVu  = (unsigned short*)(ws + 12349952);      // 2,764,800 bf16
    unsigned short* Ou    = (unsigned short*)(ws + 13732352);      // 921,600 bf16
    unsigned short* H1u   = (unsigned short*)(ws + 14193152);      // 7,372,800 bf16
    float* Y              = ws + 17879552;                         // 921,600 f32
    float* Y2             = ws + 18801152;                         // 921,600 f32
    float* T1             = ws + 19722752;                         // 921,600 f32

    const int NVROWS = BQ * LVTOT;           // 71,284
    dim3 blk(256);
    dim3 gTok(29, 2);                        // 3600-row x 256-col GEMM grid (128x128 tiles)

    // ---- ca: MSDeformAttn ----
    k_mgemm<256, 256, MODE_VALUE, 0, 1><<<dim3((NVROWS + 127) / 128, 2), blk, 0, stream>>>(memory, vproj_w, vproj_b, valueU, NVROWS);
    k_mgemm<256, 256, MODE_NORMAL, 0, 0><<<gTok, blk, 0, stream>>>(tgt, off_w, off_b, off, NTOK);
    k_mgemm<256, 256, MODE_NORMAL, 0, 0><<<dim3(29, 1), blk, 0, stream>>>(tgt, aw_w, aw_b, aw, NTOK);
    k_sample<<<45 * 32, blk, 0, stream>>>(trp, off, aw, valueU, accU);
    k_mgemm<256, 256, MODE_NORMAL, 1, 0><<<gTok, blk, 0, stream>>>(accU, oproj_w, oproj_b, T1, NTOK);
    k_res_ln<<<NTOK, blk, 0, stream>>>(T1, tgt, ln1_g, ln1_b, X);

    // ---- sa ----
    k_mgemm<256, 256, MODE_QKV, 0, 1><<<dim3(29, 6), blk, 0, stream>>>(X, sa_in_w, sa_in_b, QKVu, NTOK);
    k_attn3<<<32 * NQC3, blk, 0, stream>>>(QKVu, QKVu + 921600, QKVu + 1843200, Ou);
    k_mgemm<256, 256, MODE_NORMAL, 1, 0><<<gTok, blk, 0, stream>>>(Ou, sa_out_w, sa_out_b, T1, NTOK);
    k_res_ln<<<NTOK, blk, 0, stream>>>(T1, X, ln2_g, ln2_b, X);

    // ---- ffn ----
    k_mgemm<256, 256, MODE_RELU, 0, 1><<<dim3(29, 16), blk, 0, stream>>>(X, l1_w, l1_b, H1u, NTOK);
    k_mgemm<1024, 2048, MODE_NORMAL, 1, 0><<<gTok, blk, 0, stream>>>(H1u, l2_w, l2_b, Y, NTOK);
    k_mgemm<1024, 2048, MODE_NORMAL, 1, 0><<<gTok, blk, 0, stream>>>(H1u + 1024, l2_w + 1024, (const float*)nullptr, Y2, NTOK);
    k_res_ln2<<<NTOK, blk, 0, stream>>>(Y, Y2, X, ln3_g, ln3_b, X);

    // ---- sa3 ----
    k_mgemm<256, 256, MODE_QKV, 0, 1><<<dim3(29, 6), blk, 0, stream>>>(X, sa3_in_w, sa3_in_b, QKVu, NTOK);
    k_attn3<<<32 * NQC3, blk, 0, stream>>>(QKVu, QKVu + 921600, QKVu + 1843200, Ou);
    k_mgemm<256, 256, MODE_NORMAL, 1, 0><<<gTok, blk, 0, stream>>>(Ou, sa3_out_w, sa3_out_b, T1, NTOK);
    k_res_ln<<<NTOK, blk, 0, stream>>>(T1, X, ln5_g, ln5_b, X);

    // ---- ffn3 ----
    k_mgemm<256, 256, MODE_RELU, 0, 1><<<dim3(29, 16), blk, 0, stream>>>(X, l31_w, l31_b, H1u, NTOK);
    k_mgemm<1024, 2048, MODE_NORMAL, 1, 0><<<gTok, blk, 0, stream>>>(H1u, l32_w, l32_b, Y, NTOK);
    k_mgemm<1024, 2048, MODE_NORMAL, 1, 0><<<gTok, blk, 0, stream>>>(H1u + 1024, l32_w + 1024, (const float*)nullptr, Y2, NTOK);
    k_res_ln2<<<NTOK, blk, 0, stream>>>(Y, Y2, X, ln33_g, ln33_b, (float*)d_out);
}

// Round 9
// 411.004 us; speedup vs baseline: 1.5249x; 1.5249x over previous
//
#include <hip/hip_runtime.h>
#include <math.h>

#define C 256
#define DH 32
#define NH 8
#define NL 4
#define NP 4
#define BQ 4
#define LQ 900
#define LVTOT 17821
#define DFFN 2048
#define NTOK (BQ*LQ)          // 3600 token rows, token index t = lq*B + b

typedef __attribute__((ext_vector_type(8))) short bf8_t;    // 8 bf16 (4 VGPRs)
typedef __attribute__((ext_vector_type(4))) float f4_t;     // MFMA acc
typedef __attribute__((ext_vector_type(8))) unsigned short us8_t;
typedef __attribute__((ext_vector_type(4))) unsigned short us4_t;

// ---------------- helpers ----------------
__device__ __forceinline__ unsigned short f2bf(float f) {
    unsigned int u = __float_as_uint(f);
    u += 0x7fffu + ((u >> 16) & 1u);   // round-to-nearest-even
    return (unsigned short)(u >> 16);
}
__device__ __forceinline__ float b2f(unsigned short u) {
    return __uint_as_float(((unsigned int)u) << 16);
}

// ---------------- bf16 MFMA GEMM: Y = act(A @ W^T + b) ----------------
// A: [nrows][KS] fp32 (AB=0) or bf16 (AB=1); W: [OC][KS] fp32.
// Output f32 (OB=0) or bf16 (OB=1). Tile 128x64, 4 waves 2x2, K-step 32.
// (128x128 tried in R8: halves block count on M=3600 GEMMs -> occupancy loss. Keep 128x64.)
enum { MODE_NORMAL = 0, MODE_RELU = 1, MODE_VALUE = 2, MODE_QKV = 3 };

#define LDP 72   // LDS row stride in bf16 elems (144 B = 9*16B: aligned b128)

template<int K, int KS, int MODE, int AB, int OB>
__global__ void k_mgemm(const void* __restrict__ A_, const float* __restrict__ W,
                        const float* __restrict__ bias, void* __restrict__ Y_, int nrows) {
    __shared__ unsigned short Ash[128 * LDP];
    __shared__ unsigned short Bsh[64 * LDP];
    int t = threadIdx.x;
    int lane = t & 63, w = t >> 6;
    int wm = w & 1, wn = w >> 1;
    int r0 = blockIdx.x * 128;
    int c0 = blockIdx.y * 64;

    f4_t acc[4][2];
#pragma unroll
    for (int mt = 0; mt < 4; ++mt)
#pragma unroll
        for (int nt = 0; nt < 2; ++nt) acc[mt][nt] = (f4_t)0.f;

    int arow = t >> 1;
    int akoff = (t & 1) * 16;
    int asrc = min(r0 + arow, nrows - 1);
    const float* aptrf = (const float*)A_ + (size_t)asrc * KS + akoff;
    const unsigned short* aptrh = (const unsigned short*)A_ + (size_t)asrc * KS + akoff;
    unsigned short* adst = &Ash[arow * LDP + akoff];

    int brow = t >> 2;
    int bkoff = (t & 3) * 8;
    const float* bptr = W + (size_t)(c0 + brow) * KS + bkoff;
    unsigned short* bdst = &Bsh[brow * LDP + bkoff];

    int lr = lane & 15, kg = lane >> 4;

    for (int k0 = 0; k0 < K; k0 += 32) {
        __syncthreads();
        if (AB) {
            *(us8_t*)(adst) = *(const us8_t*)(aptrh + k0);
            *(us8_t*)(adst + 8) = *(const us8_t*)(aptrh + k0 + 8);
        } else {
            float4 av0 = *(const float4*)(aptrf + k0);
            float4 av1 = *(const float4*)(aptrf + k0 + 4);
            float4 av2 = *(const float4*)(aptrf + k0 + 8);
            float4 av3 = *(const float4*)(aptrf + k0 + 12);
            us8_t u0, u1;
            u0[0]=f2bf(av0.x); u0[1]=f2bf(av0.y); u0[2]=f2bf(av0.z); u0[3]=f2bf(av0.w);
            u0[4]=f2bf(av1.x); u0[5]=f2bf(av1.y); u0[6]=f2bf(av1.z); u0[7]=f2bf(av1.w);
            u1[0]=f2bf(av2.x); u1[1]=f2bf(av2.y); u1[2]=f2bf(av2.z); u1[3]=f2bf(av2.w);
            u1[4]=f2bf(av3.x); u1[5]=f2bf(av3.y); u1[6]=f2bf(av3.z); u1[7]=f2bf(av3.w);
            *(us8_t*)(adst) = u0;
            *(us8_t*)(adst + 8) = u1;
        }
        {
            float4 bv0 = *(const float4*)(bptr + k0);
            float4 bv1 = *(const float4*)(bptr + k0 + 4);
            us8_t u;
            u[0]=f2bf(bv0.x); u[1]=f2bf(bv0.y); u[2]=f2bf(bv0.z); u[3]=f2bf(bv0.w);
            u[4]=f2bf(bv1.x); u[5]=f2bf(bv1.y); u[6]=f2bf(bv1.z); u[7]=f2bf(bv1.w);
            *(us8_t*)(bdst) = u;
        }
        __syncthreads();

        bf8_t afr[4], bfr[2];
#pragma unroll
        for (int mt = 0; mt < 4; ++mt)
            afr[mt] = *(const bf8_t*)&Ash[(wm * 64 + mt * 16 + lr) * LDP + kg * 8];
#pragma unroll
        for (int nt = 0; nt < 2; ++nt)
            bfr[nt] = *(const bf8_t*)&Bsh[(wn * 32 + nt * 16 + lr) * LDP + kg * 8];
#pragma unroll
        for (int mt = 0; mt < 4; ++mt)
#pragma unroll
            for (int nt = 0; nt < 2; ++nt)
                acc[mt][nt] = __builtin_amdgcn_mfma_f32_16x16x32_bf16(afr[mt], bfr[nt], acc[mt][nt], 0, 0, 0);
    }

#pragma unroll
    for (int mt = 0; mt < 4; ++mt) {
#pragma unroll
        for (int nt = 0; nt < 2; ++nt) {
            int col = c0 + wn * 32 + nt * 16 + lr;
            float b0 = bias ? bias[col] : 0.f;
#pragma unroll
            for (int rr = 0; rr < 4; ++rr) {
                int row = r0 + wm * 64 + mt * 16 + kg * 4 + rr;
                if (row >= nrows) continue;
                float v = acc[mt][nt][rr] + b0;
                size_t idx;
                if (MODE == MODE_NORMAL) {
                    idx = (size_t)row * (gridDim.y * 64) + col;
                } else if (MODE == MODE_RELU) {
                    v = fmaxf(v, 0.f);
                    idx = (size_t)row * (gridDim.y * 64) + col;
                } else if (MODE == MODE_VALUE) {
                    int lv = row >> 2, b = row & 3;
                    int h = col >> 5, d = col & 31;
                    idx = (((size_t)b * NH + h) * LVTOT + lv) * DH + d;
                } else { // MODE_QKV
                    int lq = row >> 2, b = row & 3;
                    int part = col >> 8, cc = col & 255;
                    int h = cc >> 5, d = cc & 31;
                    if (part == 0) v *= 0.17677669529663687f;  // 1/sqrt(32)
                    idx = (size_t)part * (BQ * NH * LQ * DH) + (((size_t)b * NH + h) * LQ + lq) * DH + d;
                }
                if (OB) ((unsigned short*)Y_)[idx] = f2bf(v);
                else    ((float*)Y_)[idx] = v;
            }
        }
    }
}

// ---------------- deformable sampling ----------------
// Block = token (grid 3600, the R7 layout that measured best). Within a head's 32 lanes:
// 4 level-groups x 8 d-lanes; each lane gathers us4 (4 dims, 8 B) for its level's 4 points
// -> 16 wide loads/lane instead of 64 x 2 B. Cross-level reduce via shfl_xor(8,16).
__global__ void k_sample(const float* __restrict__ trp, const float* __restrict__ off,
                         const float* __restrict__ awl, const unsigned short* __restrict__ value,
                         unsigned short* __restrict__ accU) {
    int r = blockIdx.x;
    int b = r & 3;
    int t = threadIdx.x;
    int h = t >> 5;
    int lane32 = t & 31;
    int l = lane32 >> 3;               // level-group
    int dl = lane32 & 7;               // d-quad: d0 = dl*4
    int d0 = dl * 4;
    const unsigned short* vb = value + ((size_t)b * NH + h) * (size_t)LVTOT * DH;

    // softmax over this head's 16 logits (redundant across the 32 lanes)
    const float* lg = awl + (size_t)r * 128 + h * 16;
    float e0,e1,e2,e3,e4,e5,e6,e7,e8,e9,e10,e11,e12,e13,e14,e15;
    {
        float4 q0 = *(const float4*)(lg);
        float4 q1 = *(const float4*)(lg + 4);
        float4 q2 = *(const float4*)(lg + 8);
        float4 q3 = *(const float4*)(lg + 12);
        float mx = fmaxf(fmaxf(fmaxf(q0.x,q0.y),fmaxf(q0.z,q0.w)),
                   fmaxf(fmaxf(fmaxf(q1.x,q1.y),fmaxf(q1.z,q1.w)),
                   fmaxf(fmaxf(fmaxf(q2.x,q2.y),fmaxf(q2.z,q2.w)),
                         fmaxf(fmaxf(q3.x,q3.y),fmaxf(q3.z,q3.w)))));
        e0=__expf(q0.x-mx); e1=__expf(q0.y-mx); e2=__expf(q0.z-mx); e3=__expf(q0.w-mx);
        e4=__expf(q1.x-mx); e5=__expf(q1.y-mx); e6=__expf(q1.z-mx); e7=__expf(q1.w-mx);
        e8=__expf(q2.x-mx); e9=__expf(q2.y-mx); e10=__expf(q2.z-mx); e11=__expf(q2.w-mx);
        e12=__expf(q3.x-mx); e13=__expf(q3.y-mx); e14=__expf(q3.z-mx); e15=__expf(q3.w-mx);
    }
    float ssum = ((e0+e1)+(e2+e3)) + ((e4+e5)+(e6+e7)) + ((e8+e9)+(e10+e11)) + ((e12+e13)+(e14+e15));
    float sinv = 1.0f / ssum;
    // this lane's level weights (compile-time-safe selects, no runtime-indexed array)
    float w0 = (l==0) ? e0 : (l==1) ? e4 : (l==2) ? e8  : e12;
    float w1 = (l==0) ? e1 : (l==1) ? e5 : (l==2) ? e9  : e13;
    float w2 = (l==0) ? e2 : (l==1) ? e6 : (l==2) ? e10 : e14;
    float w3 = (l==0) ? e3 : (l==1) ? e7 : (l==2) ? e11 : e15;
    w0 *= sinv; w1 *= sinv; w2 *= sinv; w3 *= sinv;

    int Hl = (l==0) ? 100 : (l==1) ? 50 : (l==2) ? 25 : 13;
    int Wl = (l==0) ? 134 : (l==1) ? 67 : (l==2) ? 34 : 17;
    int s  = (l==0) ? 0 : (l==1) ? 13400 : (l==2) ? 16750 : 17600;
    float fW = (float)Wl, fH = (float)Hl;

    float rx = trp[((size_t)r * NL + l) * 2 + 0];
    float ry = trp[((size_t)r * NL + l) * 2 + 1];
    const float* offr = off + (size_t)r * C + h * 32 + l * 8;

    float o0 = 0.f, o1 = 0.f, o2 = 0.f, o3 = 0.f;
#pragma unroll
    for (int p = 0; p < 4; ++p) {
        float ox = offr[p * 2 + 0];
        float oy = offr[p * 2 + 1];
        float wq = (p==0) ? w0 : (p==1) ? w1 : (p==2) ? w2 : w3;
        float x = (rx + ox / fW) * fW - 0.5f;
        float y = (ry + oy / fH) * fH - 0.5f;
        float x0 = floorf(x), y0 = floorf(y);
#pragma unroll
        for (int dy = 0; dy < 2; ++dy) {
#pragma unroll
            for (int dx = 0; dx < 2; ++dx) {
                float xi = x0 + dx, yi = y0 + dy;
                float wgt = (1.0f - fabsf(x - xi)) * (1.0f - fabsf(y - yi));
                bool valid = (xi >= 0.f) && (xi < fW) && (yi >= 0.f) && (yi < fH);
                int xic = min(max((int)xi, 0), Wl - 1);
                int yic = min(max((int)yi, 0), Hl - 1);
                float cw = (valid ? wgt : 0.f) * wq;
                us4_t v4 = *(const us4_t*)&vb[((size_t)(s + yic * Wl + xic)) * DH + d0];
                o0 += cw * b2f(v4[0]);
                o1 += cw * b2f(v4[1]);
                o2 += cw * b2f(v4[2]);
                o3 += cw * b2f(v4[3]);
            }
        }
    }
    // reduce across the 4 level-groups (xor 8, 16 inside 32-lane head group)
    o0 += __shfl_xor(o0, 8, 32); o0 += __shfl_xor(o0, 16, 32);
    o1 += __shfl_xor(o1, 8, 32); o1 += __shfl_xor(o1, 16, 32);
    o2 += __shfl_xor(o2, 8, 32); o2 += __shfl_xor(o2, 16, 32);
    o3 += __shfl_xor(o3, 8, 32); o3 += __shfl_xor(o3, 16, 32);
    if (l == 0) {
        us4_t u;
        u[0] = f2bf(o0); u[1] = f2bf(o1); u[2] = f2bf(o2); u[3] = f2bf(o3);
        *(us4_t*)&accU[(size_t)r * C + h * 32 + d0] = u;
    }
}

// ---------------- residual + LN: wave-per-row, float4 lanes, shuffle-only ----------------
// out[r] = LN(Y0[r] + (Y1?Y1[r]:0) + Xres[r]); grid = NTOK/4 blocks, 4 rows/block.
__global__ void k_res_ln(const float* __restrict__ Y0, const float* __restrict__ Y1,
                         const float* __restrict__ Xres, const float* __restrict__ g,
                         const float* __restrict__ be, float* __restrict__ out) {
    int t = threadIdx.x, wv = t >> 6, lane = t & 63;
    int r = blockIdx.x * 4 + wv;
    float4 v = ((const float4*)(Y0 + (size_t)r * C))[lane];
    float4 x = ((const float4*)(Xres + (size_t)r * C))[lane];
    v.x += x.x; v.y += x.y; v.z += x.z; v.w += x.w;
    if (Y1) {
        float4 y1 = ((const float4*)(Y1 + (size_t)r * C))[lane];
        v.x += y1.x; v.y += y1.y; v.z += y1.z; v.w += y1.w;
    }
    float s = (v.x + v.y) + (v.z + v.w);
#pragma unroll
    for (int o = 32; o > 0; o >>= 1) s += __shfl_xor(s, o, 64);
    float mean = s * (1.0f / C);
    float4 dv = make_float4(v.x - mean, v.y - mean, v.z - mean, v.w - mean);
    float q = (dv.x * dv.x + dv.y * dv.y) + (dv.z * dv.z + dv.w * dv.w);
#pragma unroll
    for (int o = 32; o > 0; o >>= 1) q += __shfl_xor(q, o, 64);
    float rstd = rsqrtf(q * (1.0f / C) + 1e-5f);
    float4 g4 = ((const float4*)g)[lane];
    float4 b4 = ((const float4*)be)[lane];
    float4 o4 = make_float4(dv.x * rstd * g4.x + b4.x, dv.y * rstd * g4.y + b4.y,
                            dv.z * rstd * g4.z + b4.z, dv.w * rstd * g4.w + b4.w);
    ((float4*)(out + (size_t)r * C))[lane] = o4;
}

// ---------------- MFMA flash attention (bf16 Q/K/V/O) ----------------
#define NQC3 15   // ceil(900/64)

__global__ __launch_bounds__(256, 1)
void k_attn3(const unsigned short* __restrict__ Q, const unsigned short* __restrict__ K,
             const unsigned short* __restrict__ V, unsigned short* __restrict__ O) {
    __shared__ unsigned short sK[4][64 * 72];   // K rows [key][d]
    __shared__ unsigned short sV[4][32 * 72];   // V^T [d][key]
    __shared__ float sPO[4][64 * 36];           // P bf16 [64q][72k] overlaid, then Obuf f32 [64q][36d]
    __shared__ float sWm[4][64], sWl[4][64];

    int blk = blockIdx.x;
    int bh = blk & 31;                 // XCD locality
    int qc = blk >> 5;
    int b = bh >> 3, h = bh & 7;
    int t = threadIdx.x;
    int w = t >> 6, lane = t & 63;
    int lr = lane & 15, g = lane >> 4;

    const unsigned short* Qb = Q + (size_t)bh * LQ * DH;
    const unsigned short* Kb = K + (size_t)bh * LQ * DH;
    const unsigned short* Vb = V + (size_t)bh * LQ * DH;

    unsigned short* Ks = sK[w];
    unsigned short* Vt = sV[w];
    unsigned short* Ps = (unsigned short*)sPO[w];

    bf8_t qf[4];
#pragma unroll
    for (int nt = 0; nt < 4; ++nt) {
        int qg = min(qc * 64 + nt * 16 + lr, LQ - 1);
        qf[nt] = *(const bf8_t*)(Qb + (size_t)qg * DH + g * 8);
    }

    float m[4], l[4];
    f4_t acc[2][4];
#pragma unroll
    for (int nt = 0; nt < 4; ++nt) {
        m[nt] = -3e38f; l[nt] = 0.f;
        acc[0][nt] = (f4_t)0.f; acc[1][nt] = (f4_t)0.f;
    }

    for (int ci = 0; ci < 4; ++ci) {
        int k0 = ci * 256 + w * 64;
        if (k0 >= LQ) break;
        int kgl = min(k0 + lane, LQ - 1);
        const unsigned short* kr = Kb + (size_t)kgl * DH;
        const unsigned short* vr = Vb + (size_t)kgl * DH;
#pragma unroll
        for (int i = 0; i < 4; ++i)
            *(us8_t*)&Ks[lane * 72 + i * 8] = *(const us8_t*)(kr + i * 8);
#pragma unroll
        for (int i = 0; i < 4; ++i) {
            us8_t v8 = *(const us8_t*)(vr + i * 8);
#pragma unroll
            for (int j = 0; j < 8; ++j)
                Vt[(i * 8 + j) * 72 + lane] = v8[j];
        }
        // ---- QK^T: S^T[64k][64q] ----
        bf8_t ka[4];
#pragma unroll
        for (int mt = 0; mt < 4; ++mt)
            ka[mt] = *(const bf8_t*)&Ks[(mt * 16 + lr) * 72 + g * 8];
        f4_t st[4][4];
#pragma unroll
        for (int mt = 0; mt < 4; ++mt)
#pragma unroll
            for (int nt = 0; nt < 4; ++nt)
                st[mt][nt] = __builtin_amdgcn_mfma_f32_16x16x32_bf16(ka[mt], qf[nt], (f4_t)0.f, 0, 0, 0);
        // ---- online softmax + P write ----
#pragma unroll
        for (int nt = 0; nt < 4; ++nt) {
            float sv[4][4];
            float cm = -3e38f;
#pragma unroll
            for (int mt = 0; mt < 4; ++mt)
#pragma unroll
                for (int rr = 0; rr < 4; ++rr) {
                    bool valid = (k0 + mt * 16 + g * 4 + rr) < LQ;
                    float s = valid ? st[mt][nt][rr] : -3e38f;
                    sv[mt][rr] = s;
                    cm = fmaxf(cm, s);
                }
            cm = fmaxf(cm, __shfl_xor(cm, 16, 64));
            cm = fmaxf(cm, __shfl_xor(cm, 32, 64));
            float mn = fmaxf(m[nt], cm);
            float sc = __expf(m[nt] - mn);
            float cs = 0.f;
#pragma unroll
            for (int mt = 0; mt < 4; ++mt) {
                us4_t pk;
#pragma unroll
                for (int rr = 0; rr < 4; ++rr) {
                    float p = (sv[mt][rr] > -1e37f) ? __expf(sv[mt][rr] - mn) : 0.f;
                    cs += p;
                    pk[rr] = f2bf(p);
                }
                *(us4_t*)&Ps[(nt * 16 + lr) * 72 + mt * 16 + g * 4] = pk;
            }
            cs += __shfl_xor(cs, 16, 64);
            cs += __shfl_xor(cs, 32, 64);
            l[nt] = l[nt] * sc + cs;
            m[nt] = mn;
            acc[0][nt] *= sc;
            acc[1][nt] *= sc;
        }
        // ---- PV: O^T[32d][64q] ----
        bf8_t va[2][2];
#pragma unroll
        for (int md = 0; md < 2; ++md)
#pragma unroll
            for (int kt = 0; kt < 2; ++kt)
                va[md][kt] = *(const bf8_t*)&Vt[(md * 16 + lr) * 72 + kt * 32 + g * 8];
#pragma unroll
        for (int nt = 0; nt < 4; ++nt)
#pragma unroll
            for (int kt = 0; kt < 2; ++kt) {
                bf8_t pb = *(const bf8_t*)&Ps[(nt * 16 + lr) * 72 + kt * 32 + g * 8];
                acc[0][nt] = __builtin_amdgcn_mfma_f32_16x16x32_bf16(va[0][kt], pb, acc[0][nt], 0, 0, 0);
                acc[1][nt] = __builtin_amdgcn_mfma_f32_16x16x32_bf16(va[1][kt], pb, acc[1][nt], 0, 0, 0);
            }
    }

    // ---- wave combine ----
    if (g == 0) {
#pragma unroll
        for (int nt = 0; nt < 4; ++nt) {
            sWm[w][nt * 16 + lr] = m[nt];
            sWl[w][nt * 16 + lr] = l[nt];
        }
    }
    __syncthreads();
    float* ob = sPO[w];
#pragma unroll
    for (int nt = 0; nt < 4; ++nt) {
        int q = nt * 16 + lr;
        float M = fmaxf(fmaxf(sWm[0][q], sWm[1][q]), fmaxf(sWm[2][q], sWm[3][q]));
        float fac = __expf(m[nt] - M);
        f4_t v0 = acc[0][nt] * fac;
        f4_t v1 = acc[1][nt] * fac;
        *(f4_t*)&ob[q * 36 + g * 4] = v0;
        *(f4_t*)&ob[q * 36 + 16 + g * 4] = v1;
    }
    __syncthreads();
    {
        int q = t >> 2, d0 = (t & 3) * 8;
        int qglob = qc * 64 + q;
        if (qglob < LQ) {
            float M = fmaxf(fmaxf(sWm[0][q], sWm[1][q]), fmaxf(sWm[2][q], sWm[3][q]));
            float L = 0.f;
#pragma unroll
            for (int w2 = 0; w2 < 4; ++w2) L += sWl[w2][q] * __expf(sWm[w2][q] - M);
            float inv = 1.0f / L;
            f4_t r0 = (f4_t)0.f, r1 = (f4_t)0.f;
#pragma unroll
            for (int w2 = 0; w2 < 4; ++w2) {
                r0 += *(f4_t*)&sPO[w2][q * 36 + d0];
                r1 += *(f4_t*)&sPO[w2][q * 36 + d0 + 4];
            }
            r0 *= inv; r1 *= inv;
            us8_t u;
#pragma unroll
            for (int j = 0; j < 4; ++j) { u[j] = f2bf(r0[j]); u[4 + j] = f2bf(r1[j]); }
            *(us8_t*)(O + ((size_t)(qglob * BQ + b)) * C + h * 32 + d0) = u;
        }
    }
}

// ---------------- launch ----------------
extern "C" void kernel_launch(void* const* d_in, const int* in_sizes, int n_in,
                              void* d_out, int out_size, void* d_ws, size_t ws_size,
                              hipStream_t stream) {
    const float* tgt      = (const float*)d_in[0];
    const float* trp      = (const float*)d_in[1];
    const float* memory   = (const float*)d_in[2];
    const float* vproj_w  = (const float*)d_in[5];  const float* vproj_b  = (const float*)d_in[6];
    const float* off_w    = (const float*)d_in[7];  const float* off_b    = (const float*)d_in[8];
    const float* aw_w     = (const float*)d_in[9];  const float* aw_b     = (const float*)d_in[10];
    const float* oproj_w  = (const float*)d_in[11]; const float* oproj_b  = (const float*)d_in[12];
    const float* ln1_g    = (const float*)d_in[13]; const float* ln1_b    = (const float*)d_in[14];
    const float* sa_in_w  = (const float*)d_in[15]; const float* sa_in_b  = (const float*)d_in[16];
    const float* sa_out_w = (const float*)d_in[17]; const float* sa_out_b = (const float*)d_in[18];
    const float* ln2_g    = (const float*)d_in[19]; const float* ln2_b    = (const float*)d_in[20];
    const float* l1_w     = (const float*)d_in[21]; const float* l1_b     = (const float*)d_in[22];
    const float* l2_w     = (const float*)d_in[23]; const float* l2_b     = (const float*)d_in[24];
    const float* ln3_g    = (const float*)d_in[25]; const float* ln3_b    = (const float*)d_in[26];
    const float* sa3_in_w = (const float*)d_in[27]; const float* sa3_in_b = (const float*)d_in[28];
    const float* sa3_out_w= (const float*)d_in[29]; const float* sa3_out_b= (const float*)d_in[30];
    const float* ln5_g    = (const float*)d_in[31]; const float* ln5_b    = (const float*)d_in[32];
    const float* l31_w    = (const float*)d_in[33]; const float* l31_b    = (const float*)d_in[34];
    const float* l32_w    = (const float*)d_in[35]; const float* l32_b    = (const float*)d_in[36];
    const float* ln33_g   = (const float*)d_in[37]; const float* ln33_b   = (const float*)d_in[38];

    float* ws = (float*)d_ws;
    float* X              = ws;                                    // 921,600 f32
    unsigned short* valueU= (unsigned short*)(ws + 921600);        // 18,248,704 bf16
    float* off            = ws + 10045952;                         // 921,600 f32
    float* aw             = ws + 10967552;                         // 460,800 f32
    unsigned short* accU  = (unsigned short*)(ws + 11428352);      // 921,600 bf16
    unsigned short* QKVu  = (unsigned short*)(ws + 12349952);      // 2,764,800 bf16
    unsigned short* Ou    = (unsigned short*)(ws + 13732352);      // 921,600 bf16
    unsigned short* H1u   = (unsigned short*)(ws + 14193152);      // 7,372,800 bf16
    float* Y              = ws + 17879552;                         // 921,600 f32
    float* Y2             = ws + 18801152;                         // 921,600 f32
    float* T1             = ws + 19722752;                         // 921,600 f32

    const int NVROWS = BQ * LVTOT;           // 71,284
    dim3 blk(256);
    dim3 gTok(29, 4);                        // 3600-row x 256-col GEMM grid (128x64 tiles)
    const float* nullb = nullptr;

    // ---- ca: MSDeformAttn ----
    k_mgemm<256, 256, MODE_VALUE, 0, 1><<<dim3((NVROWS + 127) / 128, 4), blk, 0, stream>>>(memory, vproj_w, vproj_b, valueU, NVROWS);
    k_mgemm<256, 256, MODE_NORMAL, 0, 0><<<gTok, blk, 0, stream>>>(tgt, off_w, off_b, off, NTOK);
    k_mgemm<256, 256, MODE_NORMAL, 0, 0><<<dim3(29, 2), blk, 0, stream>>>(tgt, aw_w, aw_b, aw, NTOK);
    k_sample<<<NTOK, blk, 0, stream>>>(trp, off, aw, valueU, accU);
    k_mgemm<256, 256, MODE_NORMAL, 1, 0><<<gTok, blk, 0, stream>>>(accU, oproj_w, oproj_b, T1, NTOK);
    k_res_ln<<<NTOK / 4, blk, 0, stream>>>(T1, nullptr, tgt, ln1_g, ln1_b, X);

    // ---- sa ----
    k_mgemm<256, 256, MODE_QKV, 0, 1><<<dim3(29, 12), blk, 0, stream>>>(X, sa_in_w, sa_in_b, QKVu, NTOK);
    k_attn3<<<32 * NQC3, blk, 0, stream>>>(QKVu, QKVu + 921600, QKVu + 1843200, Ou);
    k_mgemm<256, 256, MODE_NORMAL, 1, 0><<<gTok, blk, 0, stream>>>(Ou, sa_out_w, sa_out_b, T1, NTOK);
    k_res_ln<<<NTOK / 4, blk, 0, stream>>>(T1, nullptr, X, ln2_g, ln2_b, X);

    // ---- ffn ----
    k_mgemm<256, 256, MODE_RELU, 0, 1><<<dim3(29, 32), blk, 0, stream>>>(X, l1_w, l1_b, H1u, NTOK);
    k_mgemm<1024, 2048, MODE_NORMAL, 1, 0><<<gTok, blk, 0, stream>>>(H1u, l2_w, l2_b, Y, NTOK);
    k_mgemm<1024, 2048, MODE_NORMAL, 1, 0><<<gTok, blk, 0, stream>>>(H1u + 1024, l2_w + 1024, nullb, Y2, NTOK);
    k_res_ln<<<NTOK / 4, blk, 0, stream>>>(Y, Y2, X, ln3_g, ln3_b, X);

    // ---- sa3 ----
    k_mgemm<256, 256, MODE_QKV, 0, 1><<<dim3(29, 12), blk, 0, stream>>>(X, sa3_in_w, sa3_in_b, QKVu, NTOK);
    k_attn3<<<32 * NQC3, blk, 0, stream>>>(QKVu, QKVu + 921600, QKVu + 1843200, Ou);
    k_mgemm<256, 256, MODE_NORMAL, 1, 0><<<gTok, blk, 0, stream>>>(Ou, sa3_out_w, sa3_out_b, T1, NTOK);
    k_res_ln<<<NTOK / 4, blk, 0, stream>>>(T1, nullptr, X, ln5_g, ln5_b, X);

    // ---- ffn3 ----
    k_mgemm<256, 256, MODE_RELU, 0, 1><<<dim3(29, 32), blk, 0, stream>>>(X, l31_w, l31_b, H1u, NTOK);
    k_mgemm<1024, 2048, MODE_NORMAL, 1, 0><<<gTok, blk, 0, stream>>>(H1u, l32_w, l32_b, Y, NTOK);
    k_mgemm<1024, 2048, MODE_NORMAL, 1, 0><<<gTok, blk, 0, stream>>>(H1u + 1024, l32_w + 1024, nullb, Y2, NTOK);
    k_res_ln<<<NTOK / 4, blk, 0, stream>>>(Y, Y2, X, ln33_g, ln33_b, (float*)d_out);
}